// Round 11
// baseline (597.590 us; speedup 1.0000x reference)
//
#include <hip/hip_runtime.h>

#define NN 100000
#define NE 1600000
#define HD 128
#define NL 3
#define NG 256
#define NB 196          // coarse buckets of 512 nodes
#define BCAP 56         // LDS slots per bucket per tile

typedef __attribute__((ext_vector_type(8))) short short8;
typedef __attribute__((ext_vector_type(4))) float floatx4;
typedef __attribute__((ext_vector_type(2))) _Float16 half2v;

static __device__ __forceinline__ unsigned short f2bf(float f) {
    unsigned int u = __float_as_uint(f);
    u += 0x7fffu + ((u >> 16) & 1u);
    return (unsigned short)(u >> 16);
}
static __device__ __forceinline__ float bf2f(unsigned short h) {
    return __uint_as_float(((unsigned int)h) << 16);
}
static __device__ __forceinline__ float angle3(float ax, float ay, float az,
                                               float bx, float by, float bz) {
    float cx = ay*bz - az*by;
    float cy = az*bx - ax*bz;
    float cz = ax*by - ay*bx;
    float cn = sqrtf(cx*cx + cy*cy + cz*cz);
    float d  = ax*bx + ay*by + az*bz;
    return atan2f(cn, d);
}

union U32H2 { unsigned int u; half2v h; };
static __device__ __forceinline__ half2v u2h(unsigned int x) { U32H2 t; t.u = x; return t.h; }
static __device__ __forceinline__ unsigned int h2u(half2v x) { U32H2 t; t.h = x; return t.u; }

// ---------------- weight prep: f32 [K][N] -> bf16 [N][128] (transposed) ----------------

struct PrepSrcs { const float* p[14]; };

__global__ void k_prep(PrepSrcs s, unsigned short* __restrict__ dst) {
    int mat = blockIdx.y;
    int N = (mat == 13) ? 64 : 128;
    int e = blockIdx.x * 256 + threadIdx.x;
    if (e >= N * 128) return;
    int n = e >> 7, k = e & 127;
    dst[mat * 16384 + n * 128 + k] = f2bf(s.p[mat][k * N + n]);
}

// ---------------- pos+normal packed: pn[2i]=(pos,0), pn[2i+1]=(normal,0) ----------------

__global__ void k_pn(const float* __restrict__ pos, float4* __restrict__ pn, int n) {
    int i = blockIdx.x * blockDim.x + threadIdx.x;
    if (i >= n) return;
    float x = pos[3*i], y = pos[3*i+1], z = pos[3*i+2];
    float inv = 1.0f / (sqrtf(x*x + y*y + z*z) + 1e-12f);
    pn[2*i]   = make_float4(x, y, z, 0.0f);
    pn[2*i+1] = make_float4(x*inv, y*inv, z*inv, 0.0f);
}

// ---------------- two-level counting sort ----------------
// payload: w = (local_dst9 << 17) | src17  — edge id never needed downstream.

__global__ __launch_bounds__(256) void k_bcount(const int* __restrict__ ei,
                                                int* __restrict__ bcnt, int e) {
    __shared__ int cnt[NB];
    int tid = threadIdx.x;
    for (int i = tid; i < NB; i += 256) cnt[i] = 0;
    __syncthreads();
    int i0 = blockIdx.x * 4096 + tid * 16;
    if (i0 < e) {
#pragma unroll
        for (int q = 0; q < 4; q++) {
            int4 d4 = *(const int4*)(ei + NE + i0 + q * 4);
            atomicAdd(&cnt[d4.x >> 9], 1);
            atomicAdd(&cnt[d4.y >> 9], 1);
            atomicAdd(&cnt[d4.z >> 9], 1);
            atomicAdd(&cnt[d4.w >> 9], 1);
        }
    }
    __syncthreads();
    for (int i = tid; i < NB; i += 256)
        if (cnt[i]) atomicAdd(&bcnt[i], cnt[i]);
}

__global__ void k_bscan(const int* __restrict__ bcnt, int* __restrict__ bbase,
                        int* __restrict__ bcursor, int* __restrict__ starts) {
    if (threadIdx.x == 0 && blockIdx.x == 0) {
        int acc = 0;
        for (int b = 0; b < NB; b++) {
            bbase[b] = acc; bcursor[b] = acc;
            acc += bcnt[b];
        }
        bbase[NB] = acc;
        starts[NN] = NE;
    }
}

__global__ __launch_bounds__(256) void k_bscatter(const int* __restrict__ ei,
                                                  int* __restrict__ bcursor,
                                                  unsigned int* __restrict__ bids, int e) {
    __shared__ int lcnt[NB];
    __shared__ unsigned int lbuf[NB * BCAP];
    int tid = threadIdx.x;
    for (int i = tid; i < NB; i += 256) lcnt[i] = 0;
    __syncthreads();
    int i0 = blockIdx.x * 4096 + tid * 16;
    if (i0 < e) {
#pragma unroll
        for (int q = 0; q < 4; q++) {
            int4 s4 = *(const int4*)(ei + i0 + q * 4);        // src
            int4 d4 = *(const int4*)(ei + NE + i0 + q * 4);   // dst
            int ds[4] = {d4.x, d4.y, d4.z, d4.w};
            int ss[4] = {s4.x, s4.y, s4.z, s4.w};
#pragma unroll
            for (int r = 0; r < 4; r++) {
                int d = ds[r];
                int b = d >> 9;
                unsigned int w = ((unsigned int)(d & 511) << 17) | (unsigned int)ss[r];
                int pos = atomicAdd(&lcnt[b], 1);
                if (pos < BCAP) lbuf[b * BCAP + pos] = w;
                else { int p = atomicAdd(&bcursor[b], 1); bids[p] = w; }
            }
        }
    }
    __syncthreads();
    if (tid < NB) {
        int c = lcnt[tid];
        if (c > BCAP) c = BCAP;
        if (c > 0) {
            int base = atomicAdd(&bcursor[tid], c);
            for (int k = 0; k < c; k++) bids[base + k] = lbuf[tid * BCAP + k];
        }
    }
}

__global__ __launch_bounds__(256) void k_bfinal(const unsigned int* __restrict__ bids,
                                                const int* __restrict__ bbase,
                                                int* __restrict__ ssrc,
                                                int* __restrict__ sdst,
                                                int* __restrict__ starts,
                                                int* __restrict__ deg) {
    __shared__ int s1[512];
    __shared__ int s2[256];
    int tid = threadIdx.x;
    int b = blockIdx.x;
    int node0 = b << 9;
    int base0 = bbase[b];
    int cnt = bbase[b + 1] - base0;
    s1[2 * tid] = 0; s1[2 * tid + 1] = 0;
    __syncthreads();
    for (int j = tid; j < cnt; j += 256)
        atomicAdd(&s1[bids[base0 + j] >> 17], 1);
    __syncthreads();
    int a0 = s1[2 * tid], a1 = s1[2 * tid + 1];
    s2[tid] = a0 + a1;
    __syncthreads();
    for (int off = 1; off < 256; off <<= 1) {
        int v = (tid >= off) ? s2[tid - off] : 0;
        __syncthreads();
        s2[tid] += v;
        __syncthreads();
    }
    int pairBase = (tid ? s2[tid - 1] : 0);
    int e0 = base0 + pairBase;
    int e1 = e0 + a0;
    int n0 = node0 + 2 * tid;
    if (n0 < NN)     { starts[n0] = e0;     deg[n0] = a0; }
    if (n0 + 1 < NN) { starts[n0 + 1] = e1; deg[n0 + 1] = a1; }
    s1[2 * tid] = e0; s1[2 * tid + 1] = e1;
    __syncthreads();
    for (int j = tid; j < cnt; j += 256) {
        unsigned int w = bids[base0 + j];
        int loc = w >> 17;
        int src = (int)(w & 0x1ffffu);
        int p = atomicAdd(&s1[loc], 1);
        ssrc[p] = src;
        sdst[p] = node0 + loc;
    }
}

// streaming: coalesced (ssrc,sdst) reads; pn gathers are L2-resident (3.2 MB)
__global__ void k_ppf_sorted(const int* __restrict__ ssrc, const int* __restrict__ sdst,
                             const float4* __restrict__ pn,
                             uint2* __restrict__ sppf, int e) {
    int j = blockIdx.x * blockDim.x + threadIdx.x;
    if (j >= e) return;
    int s = ssrc[j];
    int d = sdst[j];
    float4 ps_ = pn[2*s], ns_ = pn[2*s+1];
    float4 pd_ = pn[2*d], nd_ = pn[2*d+1];
    float px = ps_.x - pd_.x;
    float py = ps_.y - pd_.y;
    float pz = ps_.z - pd_.z;
    float f0 = sqrtf(px*px + py*py + pz*pz);
    float f1 = angle3(nd_.x, nd_.y, nd_.z, px, py, pz);
    float f2 = angle3(ns_.x, ns_.y, ns_.z, px, py, pz);
    float f3 = angle3(nd_.x, nd_.y, nd_.z, ns_.x, ns_.y, ns_.z);
    half2v h01 = { (_Float16)f0, (_Float16)f1 };
    half2v h23 = { (_Float16)f2, (_Float16)f3 };
    uint2 w;
    w.x = h2u(h01);
    w.y = h2u(h23);
    sppf[j] = w;
}

// ---------------- node_lin first layer: u = relu(x@W1 + b1), K=16 ----------------

__global__ void k_node_lin1(const float* __restrict__ x, const float* __restrict__ W1,
                            const float* __restrict__ b1, unsigned short* __restrict__ u, int n) {
    __shared__ float sW[16 * HD];
    __shared__ float sb[HD];
    __shared__ float sx[16 * 16];
    int tid = threadIdx.x;
    for (int idx = tid; idx < 16 * HD; idx += 256) sW[idx] = W1[idx];
    if (tid < HD) sb[tid] = b1[tid];
    int r0 = blockIdx.x * 16;
    for (int idx = tid; idx < 16 * 16; idx += 256) {
        int r = r0 + (idx >> 4);
        sx[idx] = (r < n) ? x[r * 16 + (idx & 15)] : 0.0f;
    }
    __syncthreads();
    int col = tid & 127;
    int rsub = tid >> 7;
    float wcol[16];
#pragma unroll
    for (int k = 0; k < 16; k++) wcol[k] = sW[k * HD + col];
    float bb = sb[col];
    for (int rr = rsub; rr < 16; rr += 2) {
        int r = r0 + rr;
        if (r >= n) break;
        float acc = bb;
#pragma unroll
        for (int k = 0; k < 16; k++) acc = fmaf(sx[rr * 16 + k], wcol[k], acc);
        u[r * HD + col] = f2bf(fmaxf(acc, 0.0f));
    }
}

// ---------------- fused multi-stage GEMM chain, 128-row tiles ----------------
// NS back-to-back GEMM stages; weights restaged into LDS per stage; C->A
// relayout via LDS round-trip. Only the LAST stage writes global (stride NCL).
// epi: 0 none, 1 +bias, 2 +deg*bias, 3 +bias relu.

#define SKW 136
#define SKT 136

struct ChainArgs {
    const unsigned short* W[4];
    const float* bias[4];
    int epi[4];
};

template <int NS, int NCL>
__global__ __launch_bounds__(256, 2) void k_chain(
    const unsigned short* __restrict__ in, ChainArgs ca,
    const int* __restrict__ deg, unsigned short* __restrict__ out, int n) {
    __shared__ unsigned short LW[128 * SKW];
    __shared__ unsigned short LT[128 * SKT];
    int tid = threadIdx.x;
    int wave = tid >> 6, lane = tid & 63, quad = lane >> 4, m = lane & 15;
    int rowBase = wave * 32;              // within tile
    int gBase = blockIdx.x * 128;
    floatx4 z = {0.0f, 0.0f, 0.0f, 0.0f};
    short8 a[2][4];
#pragma unroll
    for (int rt = 0; rt < 2; rt++) {
        int r = gBase + rowBase + rt * 16 + m;
        int rc = r < n ? r : n - 1;
        const unsigned short* ap = in + (size_t)rc * 128 + quad * 8;
#pragma unroll
        for (int s = 0; s < 4; s++) a[rt][s] = *(const short8*)(ap + s * 32);
    }
    float dvd[2][4];
#pragma unroll
    for (int rt = 0; rt < 2; rt++)
#pragma unroll
        for (int r = 0; r < 4; r++) {
            int gr = gBase + rowBase + rt * 16 + quad * 4 + r;
            dvd[rt][r] = (float)deg[gr < n ? gr : n - 1];
        }

#pragma unroll
    for (int st = 0; st < NS; st++) {
        const int NC = (st == NS - 1) ? NCL : 128;
        for (int idx = tid; idx < NC * 16; idx += 256) {
            int c = idx >> 4, k8 = idx & 15;
            *(short8*)&LW[c * SKW + k8 * 8] = ((const short8*)ca.W[st])[idx];
        }
        if (st > 0) {
#pragma unroll
            for (int rt = 0; rt < 2; rt++) {
                const unsigned short* tp = &LT[(rowBase + rt * 16 + m) * SKT + quad * 8];
#pragma unroll
                for (int s = 0; s < 4; s++) a[rt][s] = *(const short8*)(tp + s * 32);
            }
        }
        __syncthreads();   // LW staged; LT reads done before epilogue rewrites

        floatx4 acc[2][8];
#pragma unroll
        for (int rt = 0; rt < 2; rt++)
#pragma unroll
            for (int ct = 0; ct < 8; ct++) acc[rt][ct] = z;
#pragma unroll
        for (int ct = 0; ct < NC / 16; ct++) {
            const unsigned short* bp = &LW[(ct * 16 + m) * SKW + quad * 8];
#pragma unroll
            for (int s = 0; s < 4; s++) {
                short8 b = *(const short8*)(bp + s * 32);
                acc[0][ct] = __builtin_amdgcn_mfma_f32_16x16x32_bf16(a[0][s], b, acc[0][ct], 0, 0, 0);
                acc[1][ct] = __builtin_amdgcn_mfma_f32_16x16x32_bf16(a[1][s], b, acc[1][ct], 0, 0, 0);
            }
        }
        int epi = ca.epi[st];
        const float* bptr = ca.bias[st];
#pragma unroll
        for (int ct = 0; ct < NC / 16; ct++) {
            int col = ct * 16 + m;
            float bv = epi ? bptr[col] : 0.0f;
#pragma unroll
            for (int rt = 0; rt < 2; rt++) {
#pragma unroll
                for (int r = 0; r < 4; r++) {
                    float v = acc[rt][ct][r];
                    if (epi == 1) v += bv;
                    else if (epi == 2) v += dvd[rt][r] * bv;
                    else if (epi == 3) v = fmaxf(v + bv, 0.0f);
                    unsigned short bw = f2bf(v);
                    int row = rowBase + rt * 16 + quad * 4 + r;
                    if (st == NS - 1) {
                        int gr = gBase + row;
                        if (gr < n) out[(size_t)gr * NCL + col] = bw;
                    } else {
                        LT[row * SKT + col] = bw;
                    }
                }
            }
        }
        __syncthreads();   // LT complete + LW reads done before restage
    }
}

// ---------------- edge aggregation (CSR): S[i] = sum_e relu(t[src]+ppf@W1p+b1) ----------------

#if __has_builtin(__builtin_amdgcn_fdot2)
#define HAVE_FDOT2 1
#else
#define HAVE_FDOT2 0
#endif

static __device__ __forceinline__ void agg_edge(unsigned int u, uint2 q,
                                                half2v wA0, half2v wB0, half2v wA1, half2v wB1,
                                                float2 bb, float& a0, float& a1) {
    float tlo = __uint_as_float(u << 16);
    float thi = __uint_as_float(u & 0xffff0000u);
#if HAVE_FDOT2
    half2v p01 = u2h(q.x), p23 = u2h(q.y);
    float g0 = __builtin_amdgcn_fdot2(p01, wA0,
               __builtin_amdgcn_fdot2(p23, wB0, bb.x + tlo, false), false);
    float g1 = __builtin_amdgcn_fdot2(p01, wA1,
               __builtin_amdgcn_fdot2(p23, wB1, bb.y + thi, false), false);
#else
    half2v p01 = u2h(q.x), p23 = u2h(q.y);
    float px = (float)p01.x, py = (float)p01.y, pz = (float)p23.x, pw = (float)p23.y;
    float g0 = fmaf(px, (float)wA0.x, fmaf(py, (float)wA0.y,
               fmaf(pz, (float)wB0.x, fmaf(pw, (float)wB0.y, bb.x + tlo))));
    float g1 = fmaf(px, (float)wA1.x, fmaf(py, (float)wA1.y,
               fmaf(pz, (float)wB1.x, fmaf(pw, (float)wB1.y, bb.y + thi))));
#endif
    a0 += fmaxf(g0, 0.0f);
    a1 += fmaxf(g1, 0.0f);
}

__global__ __launch_bounds__(256, 8) void k_agg(
    const int* __restrict__ starts, const int* __restrict__ ssrc,
    const uint2* __restrict__ sppf, const unsigned int* __restrict__ t,
    const float* __restrict__ W1p, const float* __restrict__ b1,
    unsigned int* __restrict__ S, int n) {
    int node = (blockIdx.x * 256 + threadIdx.x) >> 6;
    if (node >= n) return;
    int lane = threadIdx.x & 63;
    int c2 = lane * 2;
    float2 w0 = *(const float2*)(W1p + c2);
    float2 w1 = *(const float2*)(W1p + 128 + c2);
    float2 w2 = *(const float2*)(W1p + 256 + c2);
    float2 w3 = *(const float2*)(W1p + 384 + c2);
    float2 bb = *(const float2*)(b1 + c2);
    half2v wA0 = { (_Float16)w0.x, (_Float16)w1.x };
    half2v wB0 = { (_Float16)w2.x, (_Float16)w3.x };
    half2v wA1 = { (_Float16)w0.y, (_Float16)w1.y };
    half2v wB1 = { (_Float16)w2.y, (_Float16)w3.y };
    int e0 = __builtin_amdgcn_readfirstlane(starts[node]);
    int e1 = __builtin_amdgcn_readfirstlane(starts[node + 1]);
    float a0 = 0.0f, a1 = 0.0f;
    int e = e0;
    for (; e + 8 <= e1; e += 8) {
        int s0 = ssrc[e],     s1 = ssrc[e + 1], s2 = ssrc[e + 2], s3 = ssrc[e + 3];
        int s4 = ssrc[e + 4], s5 = ssrc[e + 5], s6 = ssrc[e + 6], s7 = ssrc[e + 7];
        uint2 q0 = sppf[e],     q1 = sppf[e + 1], q2 = sppf[e + 2], q3 = sppf[e + 3];
        uint2 q4 = sppf[e + 4], q5 = sppf[e + 5], q6 = sppf[e + 6], q7 = sppf[e + 7];
        unsigned int u0 = t[((unsigned)s0 << 6) | lane];
        unsigned int u1 = t[((unsigned)s1 << 6) | lane];
        unsigned int u2 = t[((unsigned)s2 << 6) | lane];
        unsigned int u3 = t[((unsigned)s3 << 6) | lane];
        unsigned int u4 = t[((unsigned)s4 << 6) | lane];
        unsigned int u5 = t[((unsigned)s5 << 6) | lane];
        unsigned int u6 = t[((unsigned)s6 << 6) | lane];
        unsigned int u7 = t[((unsigned)s7 << 6) | lane];
        agg_edge(u0, q0, wA0, wB0, wA1, wB1, bb, a0, a1);
        agg_edge(u1, q1, wA0, wB0, wA1, wB1, bb, a0, a1);
        agg_edge(u2, q2, wA0, wB0, wA1, wB1, bb, a0, a1);
        agg_edge(u3, q3, wA0, wB0, wA1, wB1, bb, a0, a1);
        agg_edge(u4, q4, wA0, wB0, wA1, wB1, bb, a0, a1);
        agg_edge(u5, q5, wA0, wB0, wA1, wB1, bb, a0, a1);
        agg_edge(u6, q6, wA0, wB0, wA1, wB1, bb, a0, a1);
        agg_edge(u7, q7, wA0, wB0, wA1, wB1, bb, a0, a1);
    }
    for (; e + 4 <= e1; e += 4) {
        int s0 = ssrc[e], s1 = ssrc[e + 1], s2 = ssrc[e + 2], s3 = ssrc[e + 3];
        uint2 q0 = sppf[e], q1 = sppf[e + 1], q2 = sppf[e + 2], q3 = sppf[e + 3];
        unsigned int u0 = t[((unsigned)s0 << 6) | lane];
        unsigned int u1 = t[((unsigned)s1 << 6) | lane];
        unsigned int u2 = t[((unsigned)s2 << 6) | lane];
        unsigned int u3 = t[((unsigned)s3 << 6) | lane];
        agg_edge(u0, q0, wA0, wB0, wA1, wB1, bb, a0, a1);
        agg_edge(u1, q1, wA0, wB0, wA1, wB1, bb, a0, a1);
        agg_edge(u2, q2, wA0, wB0, wA1, wB1, bb, a0, a1);
        agg_edge(u3, q3, wA0, wB0, wA1, wB1, bb, a0, a1);
    }
    for (; e < e1; e++) {
        int s0 = ssrc[e];
        uint2 q0 = sppf[e];
        unsigned int u0 = t[((unsigned)s0 << 6) | lane];
        agg_edge(u0, q0, wA0, wB0, wA1, wB1, bb, a0, a1);
    }
    unsigned int r = ((unsigned int)f2bf(a1) << 16) | f2bf(a0);
    S[(size_t)node * 64 + lane] = r;
}

// ---------------- head: out = v@lin2W + b, segment-summed by batch ----------------

__global__ void k_head2(const unsigned short* __restrict__ v, const float* __restrict__ W,
                        const float* __restrict__ b, const int* __restrict__ batch,
                        float* __restrict__ outg, int n) {
    __shared__ float sW[64 * 16];
    __shared__ float sb[16];
    __shared__ float sacc[64][17];
    __shared__ int sbid[64];
    int tid = threadIdx.x;
    for (int idx = tid; idx < 64 * 16; idx += 256) sW[idx] = W[idx];
    if (tid < 16) sb[tid] = b[tid];
    int r0 = blockIdx.x * 64;
    if (tid < 64) {
        int r = r0 + tid;
        sbid[tid] = (r < n) ? batch[r] : -1;
    }
    __syncthreads();
    int rl = tid >> 4, c = tid & 15;
#pragma unroll
    for (int i = 0; i < 4; i++) {
        int row = rl + i * 16;
        int r = r0 + row;
        float acc = 0.0f;
        if (r < n) {
            const unsigned int* vr = (const unsigned int*)(v + (size_t)r * 64);
            acc = sb[c];
#pragma unroll
            for (int k2 = 0; k2 < 32; k2++) {
                unsigned int u = vr[k2];
                acc = fmaf(__uint_as_float(u << 16), sW[(2 * k2) * 16 + c], acc);
                acc = fmaf(__uint_as_float(u & 0xffff0000u), sW[(2 * k2 + 1) * 16 + c], acc);
            }
        }
        sacc[row][c] = acc;
    }
    __syncthreads();
    if (tid < 16) {
        int cc = tid;
        float run = 0.0f;
        int cur = sbid[0];
        for (int row = 0; row < 64; row++) {
            int bid = sbid[row];
            if (bid != cur) {
                if (cur >= 0) atomicAdd(&outg[cur * 16 + cc], run);
                run = 0.0f;
                cur = bid;
            }
            run += sacc[row][cc];
        }
        if (cur >= 0) atomicAdd(&outg[cur * 16 + cc], run);
    }
}

// ---------------- launch ----------------

extern "C" void kernel_launch(void* const* d_in, const int* in_sizes, int n_in,
                              void* d_out, int out_size, void* d_ws, size_t ws_size,
                              hipStream_t stream) {
    (void)in_sizes; (void)n_in; (void)out_size; (void)ws_size;
    const float* x    = (const float*)d_in[0];
    const float* pos  = (const float*)d_in[1];
    const int*   ei   = (const int*)d_in[2];
    const int*   batch= (const int*)d_in[3];
    const float* nW1  = (const float*)d_in[4];
    const float* nb1  = (const float*)d_in[5];
    const float* nW2  = (const float*)d_in[6];
    const float* nb2  = (const float*)d_in[7];
    const float* lW1  = (const float*)d_in[8];
    const float* lb1  = (const float*)d_in[9];
    const float* lW2  = (const float*)d_in[10];
    const float* lb2  = (const float*)d_in[11];
    const float* gW1  = (const float*)d_in[12];
    const float* gb1  = (const float*)d_in[13];
    const float* gW2  = (const float*)d_in[14];
    const float* gb2  = (const float*)d_in[15];
    const float* l1W  = (const float*)d_in[16];
    const float* l1b  = (const float*)d_in[17];
    const float* l2W  = (const float*)d_in[18];
    const float* l2b  = (const float*)d_in[19];
    float* outg = (float*)d_out;

    char* ws = (char*)d_ws;
    size_t off = 0;
    auto alloc = [&](size_t bytes) -> void* {
        void* p = ws + off;
        off = (off + bytes + 255) & ~(size_t)255;
        return p;
    };
    unsigned short* P0 = (unsigned short*)alloc((size_t)NN * HD * 2);
    unsigned short* P1 = (unsigned short*)alloc((size_t)NN * HD * 2);
    uint2* sppf  = (uint2*)alloc((size_t)NE * 8);
    int* ssrc    = (int*)alloc((size_t)NE * 4);
    int* sdst    = (int*)alloc((size_t)NE * 4);
    float4* pn   = (float4*)alloc((size_t)NN * 32);
    int* deg     = (int*)alloc((size_t)NN * 4);
    int* starts  = (int*)alloc((size_t)(NN + 2) * 4);
    int* bcnt    = (int*)alloc((size_t)(NB + 2) * 4);
    int* bbase   = (int*)alloc((size_t)(NB + 2) * 4);
    int* bcursor = (int*)alloc((size_t)(NB + 2) * 4);
    unsigned short* pw = (unsigned short*)alloc((size_t)14 * 16384 * 2);
    // bids lives only before node_lin writes P0 -> carve from P0 (25.6MB)
    unsigned int* bids = (unsigned int*)P0;

    // prepped weight slots: 0=nW2, 1..3=W1h_l, 4..6=lW2_l, 7..9=gW1_l, 10..12=gW2_l, 13=l1W
    PrepSrcs ps;
    ps.p[0] = nW2;
    for (int l = 0; l < 3; l++) {
        ps.p[1 + l] = lW1 + (size_t)l * 132 * 128;   // W1h (first 128 rows)
        ps.p[4 + l] = lW2 + (size_t)l * 16384;
        ps.p[7 + l] = gW1 + (size_t)l * 16384;
        ps.p[10 + l] = gW2 + (size_t)l * 16384;
    }
    ps.p[13] = l1W;

    hipMemsetAsync(bcnt, 0, (size_t)(NB + 2) * 4, stream);
    hipMemsetAsync(outg, 0, (size_t)NG * 16 * 4, stream);

    k_prep<<<dim3(64, 14), 256, 0, stream>>>(ps, pw);
    k_pn<<<(NN + 255) / 256, 256, 0, stream>>>(pos, pn, NN);
    const int NTILE = (NE + 4095) / 4096;
    k_bcount<<<NTILE, 256, 0, stream>>>(ei, bcnt, NE);
    k_bscan<<<1, 64, 0, stream>>>(bcnt, bbase, bcursor, starts);
    k_bscatter<<<NTILE, 256, 0, stream>>>(ei, bcursor, bids, NE);
    k_bfinal<<<NB, 256, 0, stream>>>(bids, bbase, ssrc, sdst, starts, deg);
    k_ppf_sorted<<<(NE + 255) / 256, 256, 0, stream>>>(ssrc, sdst, pn, sppf, NE);

    // node_lin first layer: u -> P1
    k_node_lin1<<<(NN + 15) / 16, 256, 0, stream>>>(x, nW1, nb1, P1, NN);

    const int GB = (NN + 127) / 128;
    const int AGB = (NN * 64 + 255) / 256;   // one wave per node

    // entry chain: u -> h0 (@nW2+b) -> t0 (@W1h0)   (P1 -> P0)
    {
        ChainArgs ca;
        ca.W[0] = pw;                      ca.bias[0] = nb2;     ca.epi[0] = 1;
        ca.W[1] = pw + (size_t)1 * 16384;  ca.bias[1] = nullptr; ca.epi[1] = 0;
        ca.W[2] = nullptr; ca.bias[2] = nullptr; ca.epi[2] = 0;
        ca.W[3] = nullptr; ca.bias[3] = nullptr; ca.epi[3] = 0;
        k_chain<2, 128><<<GB, 256, 0, stream>>>(P1, ca, deg, P0, NN);
    }

    unsigned short* tbuf = P0;  // holds t_l
    unsigned short* sbuf = P1;  // holds S_l
    for (int l = 0; l < NL; l++) {
        const float* W1p = lW1 + (size_t)l * 132 * 128 + 128 * 128;
        const float* b1  = lb1 + l * 128;
        // S_l = aggregate(t_l)
        k_agg<<<AGB, 256, 0, stream>>>(starts, ssrc, sppf, (const unsigned int*)tbuf,
                                       W1p, b1, (unsigned int*)sbuf, NN);
        ChainArgs ca;
        ca.W[0] = pw + (size_t)(4 + l) * 16384;  ca.bias[0] = lb2 + l * 128; ca.epi[0] = 2;
        ca.W[1] = pw + (size_t)(7 + l) * 16384;  ca.bias[1] = gb1 + l * 128; ca.epi[1] = 3;
        ca.W[2] = pw + (size_t)(10 + l) * 16384; ca.bias[2] = gb2 + l * 128; ca.epi[2] = 3;
        if (l < NL - 1) {
            ca.W[3] = pw + (size_t)(2 + l) * 16384;  // W1h_{l+1}
            ca.bias[3] = nullptr; ca.epi[3] = 0;
            k_chain<4, 128><<<GB, 256, 0, stream>>>(sbuf, ca, deg, tbuf, NN);
        } else {
            ca.W[3] = pw + (size_t)13 * 16384;       // l1W (NC=64)
            ca.bias[3] = l1b; ca.epi[3] = 3;
            k_chain<4, 64><<<GB, 256, 0, stream>>>(sbuf, ca, deg, tbuf, NN);
        }
    }
    // out = v @ lin2W + lin2b, segment-sum by batch   (v in tbuf, stride 64)
    k_head2<<<(NN + 63) / 64, 256, 0, stream>>>(tbuf, l2W, l2b, batch, outg, NN);
}

// Round 12
// 523.720 us; speedup vs baseline: 1.1410x; 1.1410x over previous
//
#include <hip/hip_runtime.h>

#define NN 100000
#define NE 1600000
#define HD 128
#define NL 3
#define NG 256
#define NB 196          // coarse buckets of 512 nodes
#define BCAP 56         // LDS slots per bucket per tile

typedef __attribute__((ext_vector_type(8))) short short8;
typedef __attribute__((ext_vector_type(4))) float floatx4;
typedef __attribute__((ext_vector_type(2))) _Float16 half2v;

static __device__ __forceinline__ unsigned short f2bf(float f) {
    unsigned int u = __float_as_uint(f);
    u += 0x7fffu + ((u >> 16) & 1u);
    return (unsigned short)(u >> 16);
}
static __device__ __forceinline__ float bf2f(unsigned short h) {
    return __uint_as_float(((unsigned int)h) << 16);
}
static __device__ __forceinline__ float angle3(float ax, float ay, float az,
                                               float bx, float by, float bz) {
    float cx = ay*bz - az*by;
    float cy = az*bx - ax*bz;
    float cz = ax*by - ay*bx;
    float cn = sqrtf(cx*cx + cy*cy + cz*cz);
    float d  = ax*bx + ay*by + az*bz;
    return atan2f(cn, d);
}

union U32H2 { unsigned int u; half2v h; };
static __device__ __forceinline__ half2v u2h(unsigned int x) { U32H2 t; t.u = x; return t.h; }
static __device__ __forceinline__ unsigned int h2u(half2v x) { U32H2 t; t.h = x; return t.u; }

// ---------------- weight prep: f32 [K][N] -> bf16 [N][128] (transposed) ----------------

struct PrepSrcs { const float* p[14]; };

__global__ void k_prep(PrepSrcs s, unsigned short* __restrict__ dst) {
    int mat = blockIdx.y;
    int N = (mat == 13) ? 64 : 128;
    int e = blockIdx.x * 256 + threadIdx.x;
    if (e >= N * 128) return;
    int n = e >> 7, k = e & 127;
    dst[mat * 16384 + n * 128 + k] = f2bf(s.p[mat][k * N + n]);
}

// ---------------- pos+normal packed: pn[2i]=(pos,0), pn[2i+1]=(normal,0) ----------------

__global__ void k_pn(const float* __restrict__ pos, float4* __restrict__ pn, int n) {
    int i = blockIdx.x * blockDim.x + threadIdx.x;
    if (i >= n) return;
    float x = pos[3*i], y = pos[3*i+1], z = pos[3*i+2];
    float inv = 1.0f / (sqrtf(x*x + y*y + z*z) + 1e-12f);
    pn[2*i]   = make_float4(x, y, z, 0.0f);
    pn[2*i+1] = make_float4(x*inv, y*inv, z*inv, 0.0f);
}

// ---------------- two-level counting sort ----------------
// payload: w = (local_dst9 << 17) | src17  — edge id never needed downstream.

__global__ __launch_bounds__(256) void k_bcount(const int* __restrict__ ei,
                                                int* __restrict__ bcnt, int e) {
    __shared__ int cnt[NB];
    int tid = threadIdx.x;
    for (int i = tid; i < NB; i += 256) cnt[i] = 0;
    __syncthreads();
    int i0 = blockIdx.x * 4096 + tid * 16;
    if (i0 < e) {
#pragma unroll
        for (int q = 0; q < 4; q++) {
            int4 d4 = *(const int4*)(ei + NE + i0 + q * 4);
            atomicAdd(&cnt[d4.x >> 9], 1);
            atomicAdd(&cnt[d4.y >> 9], 1);
            atomicAdd(&cnt[d4.z >> 9], 1);
            atomicAdd(&cnt[d4.w >> 9], 1);
        }
    }
    __syncthreads();
    for (int i = tid; i < NB; i += 256)
        if (cnt[i]) atomicAdd(&bcnt[i], cnt[i]);
}

__global__ void k_bscan(const int* __restrict__ bcnt, int* __restrict__ bbase,
                        int* __restrict__ bcursor, int* __restrict__ starts) {
    if (threadIdx.x == 0 && blockIdx.x == 0) {
        int acc = 0;
        for (int b = 0; b < NB; b++) {
            bbase[b] = acc; bcursor[b] = acc;
            acc += bcnt[b];
        }
        bbase[NB] = acc;
        starts[NN] = NE;
    }
}

__global__ __launch_bounds__(256) void k_bscatter(const int* __restrict__ ei,
                                                  int* __restrict__ bcursor,
                                                  unsigned int* __restrict__ bids, int e) {
    __shared__ int lcnt[NB];
    __shared__ unsigned int lbuf[NB * BCAP];
    int tid = threadIdx.x;
    for (int i = tid; i < NB; i += 256) lcnt[i] = 0;
    __syncthreads();
    int i0 = blockIdx.x * 4096 + tid * 16;
    if (i0 < e) {
#pragma unroll
        for (int q = 0; q < 4; q++) {
            int4 s4 = *(const int4*)(ei + i0 + q * 4);        // src
            int4 d4 = *(const int4*)(ei + NE + i0 + q * 4);   // dst
            int ds[4] = {d4.x, d4.y, d4.z, d4.w};
            int ss[4] = {s4.x, s4.y, s4.z, s4.w};
#pragma unroll
            for (int r = 0; r < 4; r++) {
                int d = ds[r];
                int b = d >> 9;
                unsigned int w = ((unsigned int)(d & 511) << 17) | (unsigned int)ss[r];
                int pos = atomicAdd(&lcnt[b], 1);
                if (pos < BCAP) lbuf[b * BCAP + pos] = w;
                else { int p = atomicAdd(&bcursor[b], 1); bids[p] = w; }
            }
        }
    }
    __syncthreads();
    if (tid < NB) {
        int c = lcnt[tid];
        if (c > BCAP) c = BCAP;
        if (c > 0) {
            int base = atomicAdd(&bcursor[tid], c);
            for (int k = 0; k < c; k++) bids[base + k] = lbuf[tid * BCAP + k];
        }
    }
}

__global__ __launch_bounds__(256) void k_bfinal(const unsigned int* __restrict__ bids,
                                                const int* __restrict__ bbase,
                                                int* __restrict__ ssrc,
                                                int* __restrict__ sdst,
                                                int* __restrict__ starts,
                                                int* __restrict__ deg) {
    __shared__ int s1[512];
    __shared__ int s2[256];
    int tid = threadIdx.x;
    int b = blockIdx.x;
    int node0 = b << 9;
    int base0 = bbase[b];
    int cnt = bbase[b + 1] - base0;
    s1[2 * tid] = 0; s1[2 * tid + 1] = 0;
    __syncthreads();
    for (int j = tid; j < cnt; j += 256)
        atomicAdd(&s1[bids[base0 + j] >> 17], 1);
    __syncthreads();
    int a0 = s1[2 * tid], a1 = s1[2 * tid + 1];
    s2[tid] = a0 + a1;
    __syncthreads();
    for (int off = 1; off < 256; off <<= 1) {
        int v = (tid >= off) ? s2[tid - off] : 0;
        __syncthreads();
        s2[tid] += v;
        __syncthreads();
    }
    int pairBase = (tid ? s2[tid - 1] : 0);
    int e0 = base0 + pairBase;
    int e1 = e0 + a0;
    int n0 = node0 + 2 * tid;
    if (n0 < NN)     { starts[n0] = e0;     deg[n0] = a0; }
    if (n0 + 1 < NN) { starts[n0 + 1] = e1; deg[n0 + 1] = a1; }
    s1[2 * tid] = e0; s1[2 * tid + 1] = e1;
    __syncthreads();
    for (int j = tid; j < cnt; j += 256) {
        unsigned int w = bids[base0 + j];
        int loc = w >> 17;
        int src = (int)(w & 0x1ffffu);
        int p = atomicAdd(&s1[loc], 1);
        ssrc[p] = src;
        sdst[p] = node0 + loc;
    }
}

// streaming: coalesced (ssrc,sdst) reads; pn gathers are L2-resident (3.2 MB)
__global__ void k_ppf_sorted(const int* __restrict__ ssrc, const int* __restrict__ sdst,
                             const float4* __restrict__ pn,
                             uint2* __restrict__ sppf, int e) {
    int j = blockIdx.x * blockDim.x + threadIdx.x;
    if (j >= e) return;
    int s = ssrc[j];
    int d = sdst[j];
    float4 ps_ = pn[2*s], ns_ = pn[2*s+1];
    float4 pd_ = pn[2*d], nd_ = pn[2*d+1];
    float px = ps_.x - pd_.x;
    float py = ps_.y - pd_.y;
    float pz = ps_.z - pd_.z;
    float f0 = sqrtf(px*px + py*py + pz*pz);
    float f1 = angle3(nd_.x, nd_.y, nd_.z, px, py, pz);
    float f2 = angle3(ns_.x, ns_.y, ns_.z, px, py, pz);
    float f3 = angle3(nd_.x, nd_.y, nd_.z, ns_.x, ns_.y, ns_.z);
    half2v h01 = { (_Float16)f0, (_Float16)f1 };
    half2v h23 = { (_Float16)f2, (_Float16)f3 };
    uint2 w;
    w.x = h2u(h01);
    w.y = h2u(h23);
    sppf[j] = w;
}

// ---------------- node_lin first layer: u = relu(x@W1 + b1), K=16 ----------------

__global__ void k_node_lin1(const float* __restrict__ x, const float* __restrict__ W1,
                            const float* __restrict__ b1, unsigned short* __restrict__ u, int n) {
    __shared__ float sW[16 * HD];
    __shared__ float sb[HD];
    __shared__ float sx[16 * 16];
    int tid = threadIdx.x;
    for (int idx = tid; idx < 16 * HD; idx += 256) sW[idx] = W1[idx];
    if (tid < HD) sb[tid] = b1[tid];
    int r0 = blockIdx.x * 16;
    for (int idx = tid; idx < 16 * 16; idx += 256) {
        int r = r0 + (idx >> 4);
        sx[idx] = (r < n) ? x[r * 16 + (idx & 15)] : 0.0f;
    }
    __syncthreads();
    int col = tid & 127;
    int rsub = tid >> 7;
    float wcol[16];
#pragma unroll
    for (int k = 0; k < 16; k++) wcol[k] = sW[k * HD + col];
    float bb = sb[col];
    for (int rr = rsub; rr < 16; rr += 2) {
        int r = r0 + rr;
        if (r >= n) break;
        float acc = bb;
#pragma unroll
        for (int k = 0; k < 16; k++) acc = fmaf(sx[rr * 16 + k], wcol[k], acc);
        u[r * HD + col] = f2bf(fmaxf(acc, 0.0f));
    }
}

// ---------------- fused multi-stage GEMM chain, 128-row tiles, SINGLE LDS buffer ------
// LB serves as both the weight tile and the C->A relayout buffer, time-sliced by
// barriers (A-frags and accumulators live in registers across the swaps). LDS
// ~37 KB -> 4 blocks/CU, whole grid co-resident; cross-block overlap hides the
// per-stage weight-staging latency that 2-block occupancy exposed (R11: 16% occ).
// epi: 0 none, 1 +bias, 2 +deg*bias, 3 +bias relu.

#define SKT 136

struct ChainArgs {
    const unsigned short* W[4];
    const float* bias[4];
    int epi[4];
};

template <int NS, int NCL>
__global__ __launch_bounds__(256, 4) void k_chain(
    const unsigned short* __restrict__ in, ChainArgs ca,
    const int* __restrict__ deg, unsigned short* __restrict__ out, int n) {
    __shared__ unsigned short LB[128 * SKT];
    __shared__ float sbias[NS][128];
    int tid = threadIdx.x;
    int wave = tid >> 6, lane = tid & 63, quad = lane >> 4, m = lane & 15;
    int rowBase = wave * 32;              // within tile
    int gBase = blockIdx.x * 128;
    floatx4 z = {0.0f, 0.0f, 0.0f, 0.0f};
    short8 a[2][4];
#pragma unroll
    for (int rt = 0; rt < 2; rt++) {
        int r = gBase + rowBase + rt * 16 + m;
        int rc = r < n ? r : n - 1;
        const unsigned short* ap = in + (size_t)rc * 128 + quad * 8;
#pragma unroll
        for (int s = 0; s < 4; s++) a[rt][s] = *(const short8*)(ap + s * 32);
    }
    if (tid < 128) {
#pragma unroll
        for (int s = 0; s < NS; s++)
            if (ca.epi[s]) sbias[s][tid] = ca.bias[s][tid];
    }
    float dvd[2][4];
#pragma unroll
    for (int rt = 0; rt < 2; rt++)
#pragma unroll
        for (int r = 0; r < 4; r++) {
            int gr = gBase + rowBase + rt * 16 + quad * 4 + r;
            dvd[rt][r] = (float)deg[gr < n ? gr : n - 1];
        }

#pragma unroll
    for (int st = 0; st < NS; st++) {
        const int NC = (st == NS - 1) ? NCL : 128;
        if (st > 0) {
            // A-frags from LB (C of previous stage; C-writes fenced by loop-end barrier)
#pragma unroll
            for (int rt = 0; rt < 2; rt++) {
                const unsigned short* tp = &LB[(rowBase + rt * 16 + m) * SKT + quad * 8];
#pragma unroll
                for (int s = 0; s < 4; s++) a[rt][s] = *(const short8*)(tp + s * 32);
            }
            __syncthreads();   // A reads done before W overwrites LB
        }
        // stage weights into LB
        for (int idx = tid; idx < NC * 16; idx += 256) {
            int c = idx >> 4, k8 = idx & 15;
            *(short8*)&LB[c * SKT + k8 * 8] = ((const short8*)ca.W[st])[idx];
        }
        __syncthreads();   // W staged

        floatx4 acc[2][8];
#pragma unroll
        for (int rt = 0; rt < 2; rt++)
#pragma unroll
            for (int ct = 0; ct < 8; ct++) acc[rt][ct] = z;
#pragma unroll
        for (int ct = 0; ct < NC / 16; ct++) {
            const unsigned short* bp = &LB[(ct * 16 + m) * SKT + quad * 8];
#pragma unroll
            for (int s = 0; s < 4; s++) {
                short8 b = *(const short8*)(bp + s * 32);
                acc[0][ct] = __builtin_amdgcn_mfma_f32_16x16x32_bf16(a[0][s], b, acc[0][ct], 0, 0, 0);
                acc[1][ct] = __builtin_amdgcn_mfma_f32_16x16x32_bf16(a[1][s], b, acc[1][ct], 0, 0, 0);
            }
        }
        __syncthreads();   // B reads done before C overwrites LB

        int epi = ca.epi[st];
#pragma unroll
        for (int ct = 0; ct < NC / 16; ct++) {
            int col = ct * 16 + m;
            float bv = epi ? sbias[st][col] : 0.0f;
#pragma unroll
            for (int rt = 0; rt < 2; rt++) {
#pragma unroll
                for (int r = 0; r < 4; r++) {
                    float v = acc[rt][ct][r];
                    if (epi == 1) v += bv;
                    else if (epi == 2) v += dvd[rt][r] * bv;
                    else if (epi == 3) v = fmaxf(v + bv, 0.0f);
                    unsigned short bw = f2bf(v);
                    int row = rowBase + rt * 16 + quad * 4 + r;
                    if (st == NS - 1) {
                        int gr = gBase + row;
                        if (gr < n) out[(size_t)gr * NCL + col] = bw;
                    } else {
                        LB[row * SKT + col] = bw;
                    }
                }
            }
        }
        if (st < NS - 1) __syncthreads();   // C complete before next A reads
    }
}

// ---------------- edge aggregation (CSR): S[i] = sum_e relu(t[src]+ppf@W1p+b1) ----------------

#if __has_builtin(__builtin_amdgcn_fdot2)
#define HAVE_FDOT2 1
#else
#define HAVE_FDOT2 0
#endif

static __device__ __forceinline__ void agg_edge(unsigned int u, uint2 q,
                                                half2v wA0, half2v wB0, half2v wA1, half2v wB1,
                                                float2 bb, float& a0, float& a1) {
    float tlo = __uint_as_float(u << 16);
    float thi = __uint_as_float(u & 0xffff0000u);
#if HAVE_FDOT2
    half2v p01 = u2h(q.x), p23 = u2h(q.y);
    float g0 = __builtin_amdgcn_fdot2(p01, wA0,
               __builtin_amdgcn_fdot2(p23, wB0, bb.x + tlo, false), false);
    float g1 = __builtin_amdgcn_fdot2(p01, wA1,
               __builtin_amdgcn_fdot2(p23, wB1, bb.y + thi, false), false);
#else
    half2v p01 = u2h(q.x), p23 = u2h(q.y);
    float px = (float)p01.x, py = (float)p01.y, pz = (float)p23.x, pw = (float)p23.y;
    float g0 = fmaf(px, (float)wA0.x, fmaf(py, (float)wA0.y,
               fmaf(pz, (float)wB0.x, fmaf(pw, (float)wB0.y, bb.x + tlo))));
    float g1 = fmaf(px, (float)wA1.x, fmaf(py, (float)wA1.y,
               fmaf(pz, (float)wB1.x, fmaf(pw, (float)wB1.y, bb.y + thi))));
#endif
    a0 += fmaxf(g0, 0.0f);
    a1 += fmaxf(g1, 0.0f);
}

__global__ __launch_bounds__(256, 8) void k_agg(
    const int* __restrict__ starts, const int* __restrict__ ssrc,
    const uint2* __restrict__ sppf, const unsigned int* __restrict__ t,
    const float* __restrict__ W1p, const float* __restrict__ b1,
    unsigned int* __restrict__ S, int n) {
    int node = (blockIdx.x * 256 + threadIdx.x) >> 6;
    if (node >= n) return;
    int lane = threadIdx.x & 63;
    int c2 = lane * 2;
    float2 w0 = *(const float2*)(W1p + c2);
    float2 w1 = *(const float2*)(W1p + 128 + c2);
    float2 w2 = *(const float2*)(W1p + 256 + c2);
    float2 w3 = *(const float2*)(W1p + 384 + c2);
    float2 bb = *(const float2*)(b1 + c2);
    half2v wA0 = { (_Float16)w0.x, (_Float16)w1.x };
    half2v wB0 = { (_Float16)w2.x, (_Float16)w3.x };
    half2v wA1 = { (_Float16)w0.y, (_Float16)w1.y };
    half2v wB1 = { (_Float16)w2.y, (_Float16)w3.y };
    int e0 = __builtin_amdgcn_readfirstlane(starts[node]);
    int e1 = __builtin_amdgcn_readfirstlane(starts[node + 1]);
    float a0 = 0.0f, a1 = 0.0f;
    int e = e0;
    for (; e + 8 <= e1; e += 8) {
        int s0 = ssrc[e],     s1 = ssrc[e + 1], s2 = ssrc[e + 2], s3 = ssrc[e + 3];
        int s4 = ssrc[e + 4], s5 = ssrc[e + 5], s6 = ssrc[e + 6], s7 = ssrc[e + 7];
        uint2 q0 = sppf[e],     q1 = sppf[e + 1], q2 = sppf[e + 2], q3 = sppf[e + 3];
        uint2 q4 = sppf[e + 4], q5 = sppf[e + 5], q6 = sppf[e + 6], q7 = sppf[e + 7];
        unsigned int u0 = t[((unsigned)s0 << 6) | lane];
        unsigned int u1 = t[((unsigned)s1 << 6) | lane];
        unsigned int u2 = t[((unsigned)s2 << 6) | lane];
        unsigned int u3 = t[((unsigned)s3 << 6) | lane];
        unsigned int u4 = t[((unsigned)s4 << 6) | lane];
        unsigned int u5 = t[((unsigned)s5 << 6) | lane];
        unsigned int u6 = t[((unsigned)s6 << 6) | lane];
        unsigned int u7 = t[((unsigned)s7 << 6) | lane];
        agg_edge(u0, q0, wA0, wB0, wA1, wB1, bb, a0, a1);
        agg_edge(u1, q1, wA0, wB0, wA1, wB1, bb, a0, a1);
        agg_edge(u2, q2, wA0, wB0, wA1, wB1, bb, a0, a1);
        agg_edge(u3, q3, wA0, wB0, wA1, wB1, bb, a0, a1);
        agg_edge(u4, q4, wA0, wB0, wA1, wB1, bb, a0, a1);
        agg_edge(u5, q5, wA0, wB0, wA1, wB1, bb, a0, a1);
        agg_edge(u6, q6, wA0, wB0, wA1, wB1, bb, a0, a1);
        agg_edge(u7, q7, wA0, wB0, wA1, wB1, bb, a0, a1);
    }
    for (; e + 4 <= e1; e += 4) {
        int s0 = ssrc[e], s1 = ssrc[e + 1], s2 = ssrc[e + 2], s3 = ssrc[e + 3];
        uint2 q0 = sppf[e], q1 = sppf[e + 1], q2 = sppf[e + 2], q3 = sppf[e + 3];
        unsigned int u0 = t[((unsigned)s0 << 6) | lane];
        unsigned int u1 = t[((unsigned)s1 << 6) | lane];
        unsigned int u2 = t[((unsigned)s2 << 6) | lane];
        unsigned int u3 = t[((unsigned)s3 << 6) | lane];
        agg_edge(u0, q0, wA0, wB0, wA1, wB1, bb, a0, a1);
        agg_edge(u1, q1, wA0, wB0, wA1, wB1, bb, a0, a1);
        agg_edge(u2, q2, wA0, wB0, wA1, wB1, bb, a0, a1);
        agg_edge(u3, q3, wA0, wB0, wA1, wB1, bb, a0, a1);
    }
    for (; e < e1; e++) {
        int s0 = ssrc[e];
        uint2 q0 = sppf[e];
        unsigned int u0 = t[((unsigned)s0 << 6) | lane];
        agg_edge(u0, q0, wA0, wB0, wA1, wB1, bb, a0, a1);
    }
    unsigned int r = ((unsigned int)f2bf(a1) << 16) | f2bf(a0);
    S[(size_t)node * 64 + lane] = r;
}

// ---------------- head: out = v@lin2W + b, segment-summed by batch ----------------

__global__ void k_head2(const unsigned short* __restrict__ v, const float* __restrict__ W,
                        const float* __restrict__ b, const int* __restrict__ batch,
                        float* __restrict__ outg, int n) {
    __shared__ float sW[64 * 16];
    __shared__ float sb[16];
    __shared__ float sacc[64][17];
    __shared__ int sbid[64];
    int tid = threadIdx.x;
    for (int idx = tid; idx < 64 * 16; idx += 256) sW[idx] = W[idx];
    if (tid < 16) sb[tid] = b[tid];
    int r0 = blockIdx.x * 64;
    if (tid < 64) {
        int r = r0 + tid;
        sbid[tid] = (r < n) ? batch[r] : -1;
    }
    __syncthreads();
    int rl = tid >> 4, c = tid & 15;
#pragma unroll
    for (int i = 0; i < 4; i++) {
        int row = rl + i * 16;
        int r = r0 + row;
        float acc = 0.0f;
        if (r < n) {
            const unsigned int* vr = (const unsigned int*)(v + (size_t)r * 64);
            acc = sb[c];
#pragma unroll
            for (int k2 = 0; k2 < 32; k2++) {
                unsigned int u = vr[k2];
                acc = fmaf(__uint_as_float(u << 16), sW[(2 * k2) * 16 + c], acc);
                acc = fmaf(__uint_as_float(u & 0xffff0000u), sW[(2 * k2 + 1) * 16 + c], acc);
            }
        }
        sacc[row][c] = acc;
    }
    __syncthreads();
    if (tid < 16) {
        int cc = tid;
        float run = 0.0f;
        int cur = sbid[0];
        for (int row = 0; row < 64; row++) {
            int bid = sbid[row];
            if (bid != cur) {
                if (cur >= 0) atomicAdd(&outg[cur * 16 + cc], run);
                run = 0.0f;
                cur = bid;
            }
            run += sacc[row][cc];
        }
        if (cur >= 0) atomicAdd(&outg[cur * 16 + cc], run);
    }
}

// ---------------- launch ----------------

extern "C" void kernel_launch(void* const* d_in, const int* in_sizes, int n_in,
                              void* d_out, int out_size, void* d_ws, size_t ws_size,
                              hipStream_t stream) {
    (void)in_sizes; (void)n_in; (void)out_size; (void)ws_size;
    const float* x    = (const float*)d_in[0];
    const float* pos  = (const float*)d_in[1];
    const int*   ei   = (const int*)d_in[2];
    const int*   batch= (const int*)d_in[3];
    const float* nW1  = (const float*)d_in[4];
    const float* nb1  = (const float*)d_in[5];
    const float* nW2  = (const float*)d_in[6];
    const float* nb2  = (const float*)d_in[7];
    const float* lW1  = (const float*)d_in[8];
    const float* lb1  = (const float*)d_in[9];
    const float* lW2  = (const float*)d_in[10];
    const float* lb2  = (const float*)d_in[11];
    const float* gW1  = (const float*)d_in[12];
    const float* gb1  = (const float*)d_in[13];
    const float* gW2  = (const float*)d_in[14];
    const float* gb2  = (const float*)d_in[15];
    const float* l1W  = (const float*)d_in[16];
    const float* l1b  = (const float*)d_in[17];
    const float* l2W  = (const float*)d_in[18];
    const float* l2b  = (const float*)d_in[19];
    float* outg = (float*)d_out;

    char* ws = (char*)d_ws;
    size_t off = 0;
    auto alloc = [&](size_t bytes) -> void* {
        void* p = ws + off;
        off = (off + bytes + 255) & ~(size_t)255;
        return p;
    };
    unsigned short* P0 = (unsigned short*)alloc((size_t)NN * HD * 2);
    unsigned short* P1 = (unsigned short*)alloc((size_t)NN * HD * 2);
    uint2* sppf  = (uint2*)alloc((size_t)NE * 8);
    int* ssrc    = (int*)alloc((size_t)NE * 4);
    int* sdst    = (int*)alloc((size_t)NE * 4);
    float4* pn   = (float4*)alloc((size_t)NN * 32);
    int* deg     = (int*)alloc((size_t)NN * 4);
    int* starts  = (int*)alloc((size_t)(NN + 2) * 4);
    int* bcnt    = (int*)alloc((size_t)(NB + 2) * 4);
    int* bbase   = (int*)alloc((size_t)(NB + 2) * 4);
    int* bcursor = (int*)alloc((size_t)(NB + 2) * 4);
    unsigned short* pw = (unsigned short*)alloc((size_t)14 * 16384 * 2);
    // bids lives only before node_lin writes P0 -> carve from P0 (25.6MB)
    unsigned int* bids = (unsigned int*)P0;

    // prepped weight slots: 0=nW2, 1..3=W1h_l, 4..6=lW2_l, 7..9=gW1_l, 10..12=gW2_l, 13=l1W
    PrepSrcs ps;
    ps.p[0] = nW2;
    for (int l = 0; l < 3; l++) {
        ps.p[1 + l] = lW1 + (size_t)l * 132 * 128;   // W1h (first 128 rows)
        ps.p[4 + l] = lW2 + (size_t)l * 16384;
        ps.p[7 + l] = gW1 + (size_t)l * 16384;
        ps.p[10 + l] = gW2 + (size_t)l * 16384;
    }
    ps.p[13] = l1W;

    hipMemsetAsync(bcnt, 0, (size_t)(NB + 2) * 4, stream);
    hipMemsetAsync(outg, 0, (size_t)NG * 16 * 4, stream);

    k_prep<<<dim3(64, 14), 256, 0, stream>>>(ps, pw);
    k_pn<<<(NN + 255) / 256, 256, 0, stream>>>(pos, pn, NN);
    const int NTILE = (NE + 4095) / 4096;
    k_bcount<<<NTILE, 256, 0, stream>>>(ei, bcnt, NE);
    k_bscan<<<1, 64, 0, stream>>>(bcnt, bbase, bcursor, starts);
    k_bscatter<<<NTILE, 256, 0, stream>>>(ei, bcursor, bids, NE);
    k_bfinal<<<NB, 256, 0, stream>>>(bids, bbase, ssrc, sdst, starts, deg);
    k_ppf_sorted<<<(NE + 255) / 256, 256, 0, stream>>>(ssrc, sdst, pn, sppf, NE);

    // node_lin first layer: u -> P1
    k_node_lin1<<<(NN + 15) / 16, 256, 0, stream>>>(x, nW1, nb1, P1, NN);

    const int GB = (NN + 127) / 128;
    const int AGB = (NN * 64 + 255) / 256;   // one wave per node

    // entry chain: u -> h0 (@nW2+b) -> t0 (@W1h0)   (P1 -> P0)
    {
        ChainArgs ca;
        ca.W[0] = pw;                      ca.bias[0] = nb2;     ca.epi[0] = 1;
        ca.W[1] = pw + (size_t)1 * 16384;  ca.bias[1] = nullptr; ca.epi[1] = 0;
        ca.W[2] = nullptr; ca.bias[2] = nullptr; ca.epi[2] = 0;
        ca.W[3] = nullptr; ca.bias[3] = nullptr; ca.epi[3] = 0;
        k_chain<2, 128><<<GB, 256, 0, stream>>>(P1, ca, deg, P0, NN);
    }

    unsigned short* tbuf = P0;  // holds t_l
    unsigned short* sbuf = P1;  // holds S_l
    for (int l = 0; l < NL; l++) {
        const float* W1p = lW1 + (size_t)l * 132 * 128 + 128 * 128;
        const float* b1  = lb1 + l * 128;
        // S_l = aggregate(t_l)
        k_agg<<<AGB, 256, 0, stream>>>(starts, ssrc, sppf, (const unsigned int*)tbuf,
                                       W1p, b1, (unsigned int*)sbuf, NN);
        ChainArgs ca;
        ca.W[0] = pw + (size_t)(4 + l) * 16384;  ca.bias[0] = lb2 + l * 128; ca.epi[0] = 2;
        ca.W[1] = pw + (size_t)(7 + l) * 16384;  ca.bias[1] = gb1 + l * 128; ca.epi[1] = 3;
        ca.W[2] = pw + (size_t)(10 + l) * 16384; ca.bias[2] = gb2 + l * 128; ca.epi[2] = 3;
        if (l < NL - 1) {
            ca.W[3] = pw + (size_t)(2 + l) * 16384;  // W1h_{l+1}
            ca.bias[3] = nullptr; ca.epi[3] = 0;
            k_chain<4, 128><<<GB, 256, 0, stream>>>(sbuf, ca, deg, tbuf, NN);
        } else {
            ca.W[3] = pw + (size_t)13 * 16384;       // l1W (NC=64)
            ca.bias[3] = l1b; ca.epi[3] = 3;
            k_chain<4, 64><<<GB, 256, 0, stream>>>(sbuf, ca, deg, tbuf, NN);
        }
    }
    // out = v @ lin2W + lin2b, segment-sum by batch   (v in tbuf, stride 64)
    k_head2<<<(NN + 63) / 64, 256, 0, stream>>>(tbuf, l2W, l2b, batch, outg, NN);
}

// Round 13
// 506.975 us; speedup vs baseline: 1.1787x; 1.0330x over previous
//
#include <hip/hip_runtime.h>

#define NN 100000
#define NE 1600000
#define HD 128
#define NL 3
#define NG 256
#define NB 196          // coarse buckets of 512 nodes
#define BCAP 56         // LDS slots per bucket per tile
#define BCAPTOT 10240   // fixed bucket capacity (mean 8192, +22 sigma)

typedef __attribute__((ext_vector_type(8))) short short8;
typedef __attribute__((ext_vector_type(4))) float floatx4;
typedef __attribute__((ext_vector_type(2))) _Float16 half2v;

static __device__ __forceinline__ unsigned short f2bf(float f) {
    unsigned int u = __float_as_uint(f);
    u += 0x7fffu + ((u >> 16) & 1u);
    return (unsigned short)(u >> 16);
}
static __device__ __forceinline__ float bf2f(unsigned short h) {
    return __uint_as_float(((unsigned int)h) << 16);
}
static __device__ __forceinline__ float angle3(float ax, float ay, float az,
                                               float bx, float by, float bz) {
    float cx = ay*bz - az*by;
    float cy = az*bx - ax*bz;
    float cz = ax*by - ay*bx;
    float cn = sqrtf(cx*cx + cy*cy + cz*cz);
    float d  = ax*bx + ay*by + az*bz;
    return atan2f(cn, d);
}

union U32H2 { unsigned int u; half2v h; };
static __device__ __forceinline__ half2v u2h(unsigned int x) { U32H2 t; t.u = x; return t.h; }
static __device__ __forceinline__ unsigned int h2u(half2v x) { U32H2 t; t.h = x; return t.u; }

// ---------------- weight prep: f32 [K][N] -> bf16 [N][128] (transposed) ----------------

struct PrepSrcs { const float* p[14]; };

__global__ void k_prep(PrepSrcs s, unsigned short* __restrict__ dst) {
    int mat = blockIdx.y;
    int N = (mat == 13) ? 64 : 128;
    int e = blockIdx.x * 256 + threadIdx.x;
    if (e >= N * 128) return;
    int n = e >> 7, k = e & 127;
    dst[mat * 16384 + n * 128 + k] = f2bf(s.p[mat][k * N + n]);
}

// ---------------- pos+normal packed: pn[2i]=(pos,0), pn[2i+1]=(normal,0) ----------------

__global__ void k_pn(const float* __restrict__ pos, float4* __restrict__ pn, int n) {
    int i = blockIdx.x * blockDim.x + threadIdx.x;
    if (i >= n) return;
    float x = pos[3*i], y = pos[3*i+1], z = pos[3*i+2];
    float inv = 1.0f / (sqrtf(x*x + y*y + z*z) + 1e-12f);
    pn[2*i]   = make_float4(x, y, z, 0.0f);
    pn[2*i+1] = make_float4(x*inv, y*inv, z*inv, 0.0f);
}

// ---------------- fixed-capacity counting sort ----------------
// payload: w = (local_dst9 << 17) | src17; bucket b owns bids[b*BCAPTOT ...).

__global__ void k_binit(int* __restrict__ bcursor) {
    int b = threadIdx.x;
    if (b < NB) bcursor[b] = b * BCAPTOT;
}

__global__ __launch_bounds__(256) void k_bscatter(const int* __restrict__ ei,
                                                  int* __restrict__ bcursor,
                                                  unsigned int* __restrict__ bids, int e) {
    __shared__ int lcnt[NB];
    __shared__ unsigned int lbuf[NB * BCAP];
    int tid = threadIdx.x;
    for (int i = tid; i < NB; i += 256) lcnt[i] = 0;
    __syncthreads();
    int i0 = blockIdx.x * 4096 + tid * 16;
    if (i0 < e) {
#pragma unroll
        for (int q = 0; q < 4; q++) {
            int4 s4 = *(const int4*)(ei + i0 + q * 4);        // src
            int4 d4 = *(const int4*)(ei + NE + i0 + q * 4);   // dst
            int ds[4] = {d4.x, d4.y, d4.z, d4.w};
            int ss[4] = {s4.x, s4.y, s4.z, s4.w};
#pragma unroll
            for (int r = 0; r < 4; r++) {
                int d = ds[r];
                int b = d >> 9;
                unsigned int w = ((unsigned int)(d & 511) << 17) | (unsigned int)ss[r];
                int pos = atomicAdd(&lcnt[b], 1);
                if (pos < BCAP) lbuf[b * BCAP + pos] = w;
                else { int p = atomicAdd(&bcursor[b], 1); bids[p] = w; }
            }
        }
    }
    __syncthreads();
    if (tid < NB) {
        int c = lcnt[tid];
        if (c > BCAP) c = BCAP;
        if (c > 0) {
            int base = atomicAdd(&bcursor[tid], c);
            for (int k = 0; k < c; k++) bids[base + k] = lbuf[tid * BCAP + k];
        }
    }
}

__global__ __launch_bounds__(256) void k_bfinal(const unsigned int* __restrict__ bids,
                                                const int* __restrict__ bcursor,
                                                int* __restrict__ ssrc,
                                                int* __restrict__ sdst,
                                                int* __restrict__ starts,
                                                int* __restrict__ deg) {
    __shared__ int s1[512];
    __shared__ int s2[256];
    int tid = threadIdx.x;
    int b = blockIdx.x;
    int node0 = b << 9;
    int base0 = b * BCAPTOT;
    int cnt = bcursor[b] - base0;
    s1[2 * tid] = 0; s1[2 * tid + 1] = 0;
    __syncthreads();
    for (int j = tid; j < cnt; j += 256)
        atomicAdd(&s1[bids[base0 + j] >> 17], 1);
    __syncthreads();
    int a0 = s1[2 * tid], a1 = s1[2 * tid + 1];
    s2[tid] = a0 + a1;
    __syncthreads();
    for (int off = 1; off < 256; off <<= 1) {
        int v = (tid >= off) ? s2[tid - off] : 0;
        __syncthreads();
        s2[tid] += v;
        __syncthreads();
    }
    int pairBase = (tid ? s2[tid - 1] : 0);
    int e0 = base0 + pairBase;
    int e1 = e0 + a0;
    int n0 = node0 + 2 * tid;
    if (n0 < NN)     { starts[n0] = e0;     deg[n0] = a0; }
    if (n0 + 1 < NN) { starts[n0 + 1] = e1; deg[n0 + 1] = a1; }
    s1[2 * tid] = e0; s1[2 * tid + 1] = e1;
    __syncthreads();
    for (int j = tid; j < cnt; j += 256) {
        unsigned int w = bids[base0 + j];
        int loc = w >> 17;
        int src = (int)(w & 0x1ffffu);
        int p = atomicAdd(&s1[loc], 1);
        ssrc[p] = src;
        sdst[p] = node0 + loc;
    }
}

// streaming over bucket windows (gaps hold poison -> guarded); pn L2-resident
__global__ void k_ppf_sorted(const int* __restrict__ ssrc, const int* __restrict__ sdst,
                             const float4* __restrict__ pn,
                             uint2* __restrict__ sppf, int npos) {
    int j = blockIdx.x * blockDim.x + threadIdx.x;
    if (j >= npos) return;
    unsigned int s = (unsigned int)ssrc[j];
    unsigned int d = (unsigned int)sdst[j];
    if (s >= NN || d >= NN) return;   // gap entry (ws poison)
    float4 ps_ = pn[2*s], ns_ = pn[2*s+1];
    float4 pd_ = pn[2*d], nd_ = pn[2*d+1];
    float px = ps_.x - pd_.x;
    float py = ps_.y - pd_.y;
    float pz = ps_.z - pd_.z;
    float f0 = sqrtf(px*px + py*py + pz*pz);
    float f1 = angle3(nd_.x, nd_.y, nd_.z, px, py, pz);
    float f2 = angle3(ns_.x, ns_.y, ns_.z, px, py, pz);
    float f3 = angle3(nd_.x, nd_.y, nd_.z, ns_.x, ns_.y, ns_.z);
    half2v h01 = { (_Float16)f0, (_Float16)f1 };
    half2v h23 = { (_Float16)f2, (_Float16)f3 };
    uint2 w;
    w.x = h2u(h01);
    w.y = h2u(h23);
    sppf[j] = w;
}

// ---------------- node_lin first layer: u = relu(x@W1 + b1), K=16 ----------------

__global__ void k_node_lin1(const float* __restrict__ x, const float* __restrict__ W1,
                            const float* __restrict__ b1, unsigned short* __restrict__ u, int n) {
    __shared__ float sW[16 * HD];
    __shared__ float sb[HD];
    __shared__ float sx[16 * 16];
    int tid = threadIdx.x;
    for (int idx = tid; idx < 16 * HD; idx += 256) sW[idx] = W1[idx];
    if (tid < HD) sb[tid] = b1[tid];
    int r0 = blockIdx.x * 16;
    for (int idx = tid; idx < 16 * 16; idx += 256) {
        int r = r0 + (idx >> 4);
        sx[idx] = (r < n) ? x[r * 16 + (idx & 15)] : 0.0f;
    }
    __syncthreads();
    int col = tid & 127;
    int rsub = tid >> 7;
    float wcol[16];
#pragma unroll
    for (int k = 0; k < 16; k++) wcol[k] = sW[k * HD + col];
    float bb = sb[col];
    for (int rr = rsub; rr < 16; rr += 2) {
        int r = r0 + rr;
        if (r >= n) break;
        float acc = bb;
#pragma unroll
        for (int k = 0; k < 16; k++) acc = fmaf(sx[rr * 16 + k], wcol[k], acc);
        u[r * HD + col] = f2bf(fmaxf(acc, 0.0f));
    }
}

// ---------------- fused multi-stage GEMM chain, 128-row tiles, SINGLE LDS buffer ------
// epi: 0 none, 1 +bias, 2 +deg*bias, 3 +bias relu.

#define SKT 136

struct ChainArgs {
    const unsigned short* W[4];
    const float* bias[4];
    int epi[4];
};

template <int NS, int NCL>
__global__ __launch_bounds__(256, 4) void k_chain(
    const unsigned short* __restrict__ in, ChainArgs ca,
    const int* __restrict__ deg, unsigned short* __restrict__ out, int n) {
    __shared__ unsigned short LB[128 * SKT];
    __shared__ float sbias[NS][128];
    int tid = threadIdx.x;
    int wave = tid >> 6, lane = tid & 63, quad = lane >> 4, m = lane & 15;
    int rowBase = wave * 32;              // within tile
    int gBase = blockIdx.x * 128;
    floatx4 z = {0.0f, 0.0f, 0.0f, 0.0f};
    short8 a[2][4];
#pragma unroll
    for (int rt = 0; rt < 2; rt++) {
        int r = gBase + rowBase + rt * 16 + m;
        int rc = r < n ? r : n - 1;
        const unsigned short* ap = in + (size_t)rc * 128 + quad * 8;
#pragma unroll
        for (int s = 0; s < 4; s++) a[rt][s] = *(const short8*)(ap + s * 32);
    }
    if (tid < 128) {
#pragma unroll
        for (int s = 0; s < NS; s++)
            if (ca.epi[s]) sbias[s][tid] = ca.bias[s][tid];
    }
    float dvd[2][4];
#pragma unroll
    for (int rt = 0; rt < 2; rt++)
#pragma unroll
        for (int r = 0; r < 4; r++) {
            int gr = gBase + rowBase + rt * 16 + quad * 4 + r;
            dvd[rt][r] = (float)deg[gr < n ? gr : n - 1];
        }

#pragma unroll
    for (int st = 0; st < NS; st++) {
        const int NC = (st == NS - 1) ? NCL : 128;
        if (st > 0) {
#pragma unroll
            for (int rt = 0; rt < 2; rt++) {
                const unsigned short* tp = &LB[(rowBase + rt * 16 + m) * SKT + quad * 8];
#pragma unroll
                for (int s = 0; s < 4; s++) a[rt][s] = *(const short8*)(tp + s * 32);
            }
            __syncthreads();   // A reads done before W overwrites LB
        }
        for (int idx = tid; idx < NC * 16; idx += 256) {
            int c = idx >> 4, k8 = idx & 15;
            *(short8*)&LB[c * SKT + k8 * 8] = ((const short8*)ca.W[st])[idx];
        }
        __syncthreads();   // W staged

        floatx4 acc[2][8];
#pragma unroll
        for (int rt = 0; rt < 2; rt++)
#pragma unroll
            for (int ct = 0; ct < 8; ct++) acc[rt][ct] = z;
#pragma unroll
        for (int ct = 0; ct < NC / 16; ct++) {
            const unsigned short* bp = &LB[(ct * 16 + m) * SKT + quad * 8];
#pragma unroll
            for (int s = 0; s < 4; s++) {
                short8 b = *(const short8*)(bp + s * 32);
                acc[0][ct] = __builtin_amdgcn_mfma_f32_16x16x32_bf16(a[0][s], b, acc[0][ct], 0, 0, 0);
                acc[1][ct] = __builtin_amdgcn_mfma_f32_16x16x32_bf16(a[1][s], b, acc[1][ct], 0, 0, 0);
            }
        }
        __syncthreads();   // B reads done before C overwrites LB

        int epi = ca.epi[st];
#pragma unroll
        for (int ct = 0; ct < NC / 16; ct++) {
            int col = ct * 16 + m;
            float bv = epi ? sbias[st][col] : 0.0f;
#pragma unroll
            for (int rt = 0; rt < 2; rt++) {
#pragma unroll
                for (int r = 0; r < 4; r++) {
                    float v = acc[rt][ct][r];
                    if (epi == 1) v += bv;
                    else if (epi == 2) v += dvd[rt][r] * bv;
                    else if (epi == 3) v = fmaxf(v + bv, 0.0f);
                    unsigned short bw = f2bf(v);
                    int row = rowBase + rt * 16 + quad * 4 + r;
                    if (st == NS - 1) {
                        int gr = gBase + row;
                        if (gr < n) out[(size_t)gr * NCL + col] = bw;
                    } else {
                        LB[row * SKT + col] = bw;
                    }
                }
            }
        }
        if (st < NS - 1) __syncthreads();   // C complete before next A reads
    }
}

// ---------------- edge aggregation: S[i] = sum_e relu(t[src]+ppf@W1p)  (b1 pre-folded into t)

#if __has_builtin(__builtin_amdgcn_fdot2)
#define HAVE_FDOT2 1
#else
#define HAVE_FDOT2 0
#endif

static __device__ __forceinline__ void agg_edge(unsigned int u, uint2 q,
                                                half2v wA0, half2v wB0, half2v wA1, half2v wB1,
                                                float& a0, float& a1) {
    float tlo = __uint_as_float(u << 16);
    float thi = __uint_as_float(u & 0xffff0000u);
#if HAVE_FDOT2
    half2v p01 = u2h(q.x), p23 = u2h(q.y);
    float g0 = __builtin_amdgcn_fdot2(p01, wA0,
               __builtin_amdgcn_fdot2(p23, wB0, tlo, false), false);
    float g1 = __builtin_amdgcn_fdot2(p01, wA1,
               __builtin_amdgcn_fdot2(p23, wB1, thi, false), false);
#else
    half2v p01 = u2h(q.x), p23 = u2h(q.y);
    float px = (float)p01.x, py = (float)p01.y, pz = (float)p23.x, pw = (float)p23.y;
    float g0 = fmaf(px, (float)wA0.x, fmaf(py, (float)wA0.y,
               fmaf(pz, (float)wB0.x, fmaf(pw, (float)wB0.y, tlo))));
    float g1 = fmaf(px, (float)wA1.x, fmaf(py, (float)wA1.y,
               fmaf(pz, (float)wB1.x, fmaf(pw, (float)wB1.y, thi))));
#endif
    a0 += fmaxf(g0, 0.0f);
    a1 += fmaxf(g1, 0.0f);
}

__global__ __launch_bounds__(256, 8) void k_agg(
    const int* __restrict__ starts, const int* __restrict__ deg,
    const int* __restrict__ ssrc,
    const uint2* __restrict__ sppf, const unsigned int* __restrict__ t,
    const float* __restrict__ W1p,
    unsigned int* __restrict__ S, int n) {
    int node = (blockIdx.x * 256 + threadIdx.x) >> 6;
    if (node >= n) return;
    int lane = threadIdx.x & 63;
    int c2 = lane * 2;
    float2 w0 = *(const float2*)(W1p + c2);
    float2 w1 = *(const float2*)(W1p + 128 + c2);
    float2 w2 = *(const float2*)(W1p + 256 + c2);
    float2 w3 = *(const float2*)(W1p + 384 + c2);
    half2v wA0 = { (_Float16)w0.x, (_Float16)w1.x };
    half2v wB0 = { (_Float16)w2.x, (_Float16)w3.x };
    half2v wA1 = { (_Float16)w0.y, (_Float16)w1.y };
    half2v wB1 = { (_Float16)w2.y, (_Float16)w3.y };
    int e0 = __builtin_amdgcn_readfirstlane(starts[node]);
    int dg = __builtin_amdgcn_readfirstlane(deg[node]);
    int e1 = e0 + dg;
    float a0 = 0.0f, a1 = 0.0f;
    int e = e0;
    for (; e + 8 <= e1; e += 8) {
        int s0 = ssrc[e],     s1 = ssrc[e + 1], s2 = ssrc[e + 2], s3 = ssrc[e + 3];
        int s4 = ssrc[e + 4], s5 = ssrc[e + 5], s6 = ssrc[e + 6], s7 = ssrc[e + 7];
        uint2 q0 = sppf[e],     q1 = sppf[e + 1], q2 = sppf[e + 2], q3 = sppf[e + 3];
        uint2 q4 = sppf[e + 4], q5 = sppf[e + 5], q6 = sppf[e + 6], q7 = sppf[e + 7];
        unsigned int u0 = t[((unsigned)s0 << 6) | lane];
        unsigned int u1 = t[((unsigned)s1 << 6) | lane];
        unsigned int u2 = t[((unsigned)s2 << 6) | lane];
        unsigned int u3 = t[((unsigned)s3 << 6) | lane];
        unsigned int u4 = t[((unsigned)s4 << 6) | lane];
        unsigned int u5 = t[((unsigned)s5 << 6) | lane];
        unsigned int u6 = t[((unsigned)s6 << 6) | lane];
        unsigned int u7 = t[((unsigned)s7 << 6) | lane];
        __asm__ __volatile__("" ::: "memory");  // force all 8 gathers issued before use
        agg_edge(u0, q0, wA0, wB0, wA1, wB1, a0, a1);
        agg_edge(u1, q1, wA0, wB0, wA1, wB1, a0, a1);
        agg_edge(u2, q2, wA0, wB0, wA1, wB1, a0, a1);
        agg_edge(u3, q3, wA0, wB0, wA1, wB1, a0, a1);
        agg_edge(u4, q4, wA0, wB0, wA1, wB1, a0, a1);
        agg_edge(u5, q5, wA0, wB0, wA1, wB1, a0, a1);
        agg_edge(u6, q6, wA0, wB0, wA1, wB1, a0, a1);
        agg_edge(u7, q7, wA0, wB0, wA1, wB1, a0, a1);
    }
    for (; e + 4 <= e1; e += 4) {
        int s0 = ssrc[e], s1 = ssrc[e + 1], s2 = ssrc[e + 2], s3 = ssrc[e + 3];
        uint2 q0 = sppf[e], q1 = sppf[e + 1], q2 = sppf[e + 2], q3 = sppf[e + 3];
        unsigned int u0 = t[((unsigned)s0 << 6) | lane];
        unsigned int u1 = t[((unsigned)s1 << 6) | lane];
        unsigned int u2 = t[((unsigned)s2 << 6) | lane];
        unsigned int u3 = t[((unsigned)s3 << 6) | lane];
        __asm__ __volatile__("" ::: "memory");
        agg_edge(u0, q0, wA0, wB0, wA1, wB1, a0, a1);
        agg_edge(u1, q1, wA0, wB0, wA1, wB1, a0, a1);
        agg_edge(u2, q2, wA0, wB0, wA1, wB1, a0, a1);
        agg_edge(u3, q3, wA0, wB0, wA1, wB1, a0, a1);
    }
    for (; e < e1; e++) {
        int s0 = ssrc[e];
        uint2 q0 = sppf[e];
        unsigned int u0 = t[((unsigned)s0 << 6) | lane];
        agg_edge(u0, q0, wA0, wB0, wA1, wB1, a0, a1);
    }
    unsigned int r = ((unsigned int)f2bf(a1) << 16) | f2bf(a0);
    S[(size_t)node * 64 + lane] = r;
}

// ---------------- head: out = v@lin2W + b, segment-summed by batch ----------------

__global__ void k_head2(const unsigned short* __restrict__ v, const float* __restrict__ W,
                        const float* __restrict__ b, const int* __restrict__ batch,
                        float* __restrict__ outg, int n) {
    __shared__ float sW[64 * 16];
    __shared__ float sb[16];
    __shared__ float sacc[64][17];
    __shared__ int sbid[64];
    int tid = threadIdx.x;
    for (int idx = tid; idx < 64 * 16; idx += 256) sW[idx] = W[idx];
    if (tid < 16) sb[tid] = b[tid];
    int r0 = blockIdx.x * 64;
    if (tid < 64) {
        int r = r0 + tid;
        sbid[tid] = (r < n) ? batch[r] : -1;
    }
    __syncthreads();
    int rl = tid >> 4, c = tid & 15;
#pragma unroll
    for (int i = 0; i < 4; i++) {
        int row = rl + i * 16;
        int r = r0 + row;
        float acc = 0.0f;
        if (r < n) {
            const unsigned int* vr = (const unsigned int*)(v + (size_t)r * 64);
            acc = sb[c];
#pragma unroll
            for (int k2 = 0; k2 < 32; k2++) {
                unsigned int u = vr[k2];
                acc = fmaf(__uint_as_float(u << 16), sW[(2 * k2) * 16 + c], acc);
                acc = fmaf(__uint_as_float(u & 0xffff0000u), sW[(2 * k2 + 1) * 16 + c], acc);
            }
        }
        sacc[row][c] = acc;
    }
    __syncthreads();
    if (tid < 16) {
        int cc = tid;
        float run = 0.0f;
        int cur = sbid[0];
        for (int row = 0; row < 64; row++) {
            int bid = sbid[row];
            if (bid != cur) {
                if (cur >= 0) atomicAdd(&outg[cur * 16 + cc], run);
                run = 0.0f;
                cur = bid;
            }
            run += sacc[row][cc];
        }
        if (cur >= 0) atomicAdd(&outg[cur * 16 + cc], run);
    }
}

// ---------------- launch ----------------

extern "C" void kernel_launch(void* const* d_in, const int* in_sizes, int n_in,
                              void* d_out, int out_size, void* d_ws, size_t ws_size,
                              hipStream_t stream) {
    (void)in_sizes; (void)n_in; (void)out_size; (void)ws_size;
    const float* x    = (const float*)d_in[0];
    const float* pos  = (const float*)d_in[1];
    const int*   ei   = (const int*)d_in[2];
    const int*   batch= (const int*)d_in[3];
    const float* nW1  = (const float*)d_in[4];
    const float* nb1  = (const float*)d_in[5];
    const float* nW2  = (const float*)d_in[6];
    const float* nb2  = (const float*)d_in[7];
    const float* lW1  = (const float*)d_in[8];
    const float* lb1  = (const float*)d_in[9];
    const float* lW2  = (const float*)d_in[10];
    const float* lb2  = (const float*)d_in[11];
    const float* gW1  = (const float*)d_in[12];
    const float* gb1  = (const float*)d_in[13];
    const float* gW2  = (const float*)d_in[14];
    const float* gb2  = (const float*)d_in[15];
    const float* l1W  = (const float*)d_in[16];
    const float* l1b  = (const float*)d_in[17];
    const float* l2W  = (const float*)d_in[18];
    const float* l2b  = (const float*)d_in[19];
    float* outg = (float*)d_out;

    const int NPOS = NB * BCAPTOT;   // 2,007,040 sorted-edge slots (with gaps)

    char* ws = (char*)d_ws;
    size_t off = 0;
    auto alloc = [&](size_t bytes) -> void* {
        void* p = ws + off;
        off = (off + bytes + 255) & ~(size_t)255;
        return p;
    };
    unsigned short* P0 = (unsigned short*)alloc((size_t)NN * HD * 2);
    unsigned short* P1 = (unsigned short*)alloc((size_t)NN * HD * 2);
    uint2* sppf  = (uint2*)alloc((size_t)NPOS * 8);
    int* ssrc    = (int*)alloc((size_t)NPOS * 4);
    float4* pn   = (float4*)alloc((size_t)NN * 32);
    int* deg     = (int*)alloc((size_t)NN * 4);
    int* starts  = (int*)alloc((size_t)(NN + 2) * 4);
    int* bcursor = (int*)alloc((size_t)(NB + 2) * 4);
    unsigned short* pw = (unsigned short*)alloc((size_t)14 * 16384 * 2);
    // bids lives only before the entry chain writes P0; sdst only before node_lin1 writes P1
    unsigned int* bids = (unsigned int*)P0;   // NPOS*4 = 8.0 MB <= 25.6 MB
    int* sdst          = (int*)P1;            // NPOS*4 = 8.0 MB <= 25.6 MB

    // prepped weight slots: 0=nW2, 1..3=W1h_l, 4..6=lW2_l, 7..9=gW1_l, 10..12=gW2_l, 13=l1W
    PrepSrcs ps;
    ps.p[0] = nW2;
    for (int l = 0; l < 3; l++) {
        ps.p[1 + l] = lW1 + (size_t)l * 132 * 128;   // W1h (first 128 rows)
        ps.p[4 + l] = lW2 + (size_t)l * 16384;
        ps.p[7 + l] = gW1 + (size_t)l * 16384;
        ps.p[10 + l] = gW2 + (size_t)l * 16384;
    }
    ps.p[13] = l1W;

    hipMemsetAsync(outg, 0, (size_t)NG * 16 * 4, stream);

    k_prep<<<dim3(64, 14), 256, 0, stream>>>(ps, pw);
    k_pn<<<(NN + 255) / 256, 256, 0, stream>>>(pos, pn, NN);
    k_binit<<<1, 256, 0, stream>>>(bcursor);
    const int NTILE = (NE + 4095) / 4096;
    k_bscatter<<<NTILE, 256, 0, stream>>>(ei, bcursor, bids, NE);
    k_bfinal<<<NB, 256, 0, stream>>>(bids, bcursor, ssrc, sdst, starts, deg);
    k_ppf_sorted<<<(NPOS + 255) / 256, 256, 0, stream>>>(ssrc, sdst, pn, sppf, NPOS);

    // node_lin first layer: u -> P1
    k_node_lin1<<<(NN + 15) / 16, 256, 0, stream>>>(x, nW1, nb1, P1, NN);

    const int GB = (NN + 127) / 128;
    const int AGB = (NN * 64 + 255) / 256;   // one wave per node

    // entry chain: u -> h0 (@nW2+nb2) -> t0 (@W1h0 + b1_0, pre-biased for agg)
    {
        ChainArgs ca;
        ca.W[0] = pw;                      ca.bias[0] = nb2;  ca.epi[0] = 1;
        ca.W[1] = pw + (size_t)1 * 16384;  ca.bias[1] = lb1;  ca.epi[1] = 1;
        ca.W[2] = nullptr; ca.bias[2] = nullptr; ca.epi[2] = 0;
        ca.W[3] = nullptr; ca.bias[3] = nullptr; ca.epi[3] = 0;
        k_chain<2, 128><<<GB, 256, 0, stream>>>(P1, ca, deg, P0, NN);
    }

    unsigned short* tbuf = P0;  // holds t_l (pre-biased with b1_l)
    unsigned short* sbuf = P1;  // holds S_l
    for (int l = 0; l < NL; l++) {
        const float* W1p = lW1 + (size_t)l * 132 * 128 + 128 * 128;
        // S_l = aggregate(t_l)
        k_agg<<<AGB, 256, 0, stream>>>(starts, deg, ssrc, sppf,
                                       (const unsigned int*)tbuf, W1p,
                                       (unsigned int*)sbuf, NN);
        ChainArgs ca;
        ca.W[0] = pw + (size_t)(4 + l) * 16384;  ca.bias[0] = lb2 + l * 128; ca.epi[0] = 2;
        ca.W[1] = pw + (size_t)(7 + l) * 16384;  ca.bias[1] = gb1 + l * 128; ca.epi[1] = 3;
        ca.W[2] = pw + (size_t)(10 + l) * 16384; ca.bias[2] = gb2 + l * 128; ca.epi[2] = 3;
        if (l < NL - 1) {
            ca.W[3] = pw + (size_t)(2 + l) * 16384;      // W1h_{l+1}
            ca.bias[3] = lb1 + (l + 1) * 128;            // pre-fold b1_{l+1}
            ca.epi[3] = 1;
            k_chain<4, 128><<<GB, 256, 0, stream>>>(sbuf, ca, deg, tbuf, NN);
        } else {
            ca.W[3] = pw + (size_t)13 * 16384;           // l1W (NC=64)
            ca.bias[3] = l1b; ca.epi[3] = 3;
            k_chain<4, 64><<<GB, 256, 0, stream>>>(sbuf, ca, deg, tbuf, NN);
        }
    }
    // out = v @ lin2W + lin2b, segment-sum by batch   (v in tbuf, stride 64)
    k_head2<<<(NN + 63) / 64, 256, 0, stream>>>(tbuf, l2W, l2b, batch, outg, NN);
}